// Round 5
// baseline (984.477 us; speedup 1.0000x reference)
//
#include <hip/hip_runtime.h>
#include <math.h>

#define EMBED  1024
#define HIDDEN 1024
#define VOCAB  32000
#define TSTEPS 64
#define NBLK   256   // 1 block per CU, all co-resident (persistent kernel)
#define HSTR   1028  // hist row stride (floats): 4-float skew/row -> broadcast
                     // rows on disjoint bank quads, gemv reads 2-way (free)
#define WSTR   68    // w3 row stride: consecutive rows 2-way aliased (free)

// ---------------------------------------------------------------------------
// ONE fused persistent kernel. R4 post-mortem: fixed ~200us harness overhead
// (unremovable); kernel 502us = phase1 ~25 + phase2 ~235 + phase3 ~240.
// Phase 3 was fat because (a) serial per-element poll loops (16 dependent LLC
// RTTs/thread/chunk) and (b) zero overlap: 131MB fcW burst after LSTM done.
//
// R5: phase 3 ELIMINATED. The LSTM staging buffer is an 8-deep LDS history
// hist[8][1028]; every 8 steps each block runs a self-contained logits
// sub-GEMM (its 128 fcW rows x 8 finished t-rows x K=1024, fcW streamed
// through LDS in K-chunks of 64) inside phase 2's idle time (~5-6us per
// group vs 3.7us/step * 8 = 30us of mostly-idle). Tail: batched poll of
// hs_pk row 63 + final group. Blocks 250..255 skip logits (32000 = 250*128).
//
// h exchange unchanged from R4: packed (tag=t+1, h) u64 agent-scope atomics
// in hs_pk[64][1024]; step t polls row t-1; tags 1..64 never match 0xAA
// poison -> no memset needed.
// ---------------------------------------------------------------------------
__global__ __launch_bounds__(256, 1) void decoder_fused(
    const int*   __restrict__ caps,
    const float* __restrict__ feat,
    const float* __restrict__ table,
    const float* __restrict__ Wih,
    const float* __restrict__ Whh,
    const float* __restrict__ bih,
    const float* __restrict__ bhh,
    const float* __restrict__ fcW,
    const float* __restrict__ fcb,
    unsigned long long* hs_pk,   // [64][1024] packed (tag,value)
    float* __restrict__ out)
{
    // arena reuse:
    //   phase 1: xs_s[64][132] (33792 B) + w16[16][132] (8448 B) = 42240 B
    //   phase 2: hist[8][1028] (32896 B) + w3[128][68]  (34816 B) = 67712 B
    __shared__ __align__(16) char arena[67712];
    __shared__ float xg_s[TSTEPS][16];
    __shared__ int   caps_s[TSTEPS];

    int tid = threadIdx.x;
    int b   = blockIdx.x;

    // ---- phase-2 weight prefetch issued first (hides HBM under phase 1)
    int lane = tid & 63;
    int wv   = tid >> 6;          // output sub-index 0..3 (one per wave)
    int g    = lane >> 4;         // gate index 0..3 (i,f,g,o)
    int c16  = lane & 15;
    int hj   = 4 * b + wv;
    const float4* wrow = (const float4*)(Whh + ((size_t)g * HIDDEN + hj) * HIDDEN);
    float4 wreg[16];
#pragma unroll
    for (int k = 0; k < 16; ++k) wreg[k] = wrow[c16 + 16 * k];

    if (tid < TSTEPS) caps_s[tid] = caps[tid];

    // ================= phase 1: xg_s[t][r] for this block's 16 columns ====
    {
        float (*xs_s)[132] = (float (*)[132])arena;            // 64 x 132
        float (*w16)[132]  = (float (*)[132])(arena + 33792);  // 16 x 132
        int jl = tid & 15;        // r = g*4+w
        int tg = tid >> 4;        // 16 groups x 4 timesteps
        float acc4[4] = {0.f, 0.f, 0.f, 0.f};
        __syncthreads();          // caps_s visible

        for (int c = 0; c < 8; ++c) {
            __syncthreads();
            for (int idx = tid; idx < 64 * 32; idx += 256) {
                int r = idx >> 5, f4 = idx & 31;
                const float* src = (r == 0)
                    ? (feat + c * 128)
                    : (table + (size_t)caps_s[r - 1] * EMBED + c * 128);
                *((float4*)&xs_s[r][f4 * 4]) = ((const float4*)src)[f4];
            }
            for (int idx = tid; idx < 16 * 32; idx += 256) {
                int r = idx >> 5, f4 = idx & 31;
                int jr = (r >> 2) * HIDDEN + 4 * b + (r & 3);
                *((float4*)&w16[r][f4 * 4]) =
                    ((const float4*)(Wih + (size_t)jr * EMBED + c * 128))[f4];
            }
            __syncthreads();
            for (int f4 = 0; f4 < 32; ++f4) {
                float4 w = *((const float4*)&w16[jl][f4 * 4]);
#pragma unroll
                for (int k = 0; k < 4; ++k) {
                    float4 x4 = *((const float4*)&xs_s[tg * 4 + k][f4 * 4]);
                    acc4[k] += w.x * x4.x + w.y * x4.y + w.z * x4.z + w.w * x4.w;
                }
            }
        }
        int jrow = (jl >> 2) * HIDDEN + 4 * b + (jl & 3);
        float bias = bih[jrow] + bhh[jrow];
#pragma unroll
        for (int k = 0; k < 4; ++k) xg_s[tg * 4 + k][jl] = acc4[k] + bias;
        __syncthreads();
    }

    // ================= phase 2: LSTM + fused logits groups =================
    float (*hist)[HSTR] = (float (*)[HSTR])arena;           // 8 x 1028
    float (*w3)[WSTR]   = (float (*)[WSTR])(arena + 32896); // 128 x 68

    // logits thread mapping: rows (tt0, tt0+1) x cols (vv, vv+64)
    int tt0 = (tid & 3) * 2;
    int vv  = tid >> 2;           // 0..63
    int v0  = b * 128;
    float fb0 = 0.f, fb1 = 0.f;
    if (b < 250) { fb0 = fcb[v0 + vv]; fb1 = fcb[v0 + vv + 64]; }

    // self-contained logits sub-GEMM for rows tg0..tg0+7 (hist[0..7])
    auto do_group = [&](int tg0) {
        float a00 = 0.f, a01 = 0.f, a10 = 0.f, a11 = 0.f;
        for (int kc = 0; kc < 16; ++kc) {
            __syncthreads();
            // stage fcW chunk [128][64] — coalesced 256B bursts per row
#pragma unroll
            for (int i = 0; i < 8; ++i) {
                int idx = tid + i * 256;
                int r = idx >> 4, f4 = idx & 15;
                *((float4*)&w3[r][f4 * 4]) =
                    ((const float4*)(fcW + (size_t)(v0 + r) * HIDDEN + kc * 64))[f4];
            }
            __syncthreads();
#pragma unroll
            for (int q4 = 0; q4 < 16; ++q4) {
                float4 ha = *((const float4*)&hist[tt0    ][kc * 64 + q4 * 4]);
                float4 hb = *((const float4*)&hist[tt0 + 1][kc * 64 + q4 * 4]);
                float4 wa = *((const float4*)&w3[vv     ][q4 * 4]);
                float4 wb = *((const float4*)&w3[vv + 64][q4 * 4]);
                a00 += wa.x * ha.x + wa.y * ha.y + wa.z * ha.z + wa.w * ha.w;
                a01 += wb.x * ha.x + wb.y * ha.y + wb.z * ha.z + wb.w * ha.w;
                a10 += wa.x * hb.x + wa.y * hb.y + wa.z * hb.z + wa.w * hb.w;
                a11 += wb.x * hb.x + wb.y * hb.y + wb.z * hb.z + wb.w * hb.w;
            }
        }
        int tr = tg0 + tt0;
        out[(size_t)tr * VOCAB + v0 + vv]            = a00 + fb0;
        out[(size_t)tr * VOCAB + v0 + vv + 64]       = a01 + fb1;
        out[(size_t)(tr + 1) * VOCAB + v0 + vv]      = a10 + fb0;
        out[(size_t)(tr + 1) * VOCAB + v0 + vv + 64] = a11 + fb1;
        __syncthreads();   // protect hist rows from next-step overwrite
    };

    float cstate = 0.f;           // live in lane 0 of each wave only
    for (int t = 0; t < TSTEPS; ++t) {
        float* dst = hist[(t - 1) & 7];   // h[t-1] lives at hist[(t-1)&7]
        if (t == 0) {
            for (int i = tid; i < HIDDEN; i += 256) dst[i] = 0.f;
        } else {
            const unsigned long long* hsrc = hs_pk + (size_t)(t - 1) * HIDDEN;
            unsigned want = (unsigned)t;   // producer stored tag (t-1)+1 = t
            unsigned long long x0 = 0, x1 = 0, x2 = 0, x3 = 0;
            int need = 0xF;
            do {
                if (need & 1) {
                    x0 = __hip_atomic_load(hsrc + tid, __ATOMIC_RELAXED,
                                           __HIP_MEMORY_SCOPE_AGENT);
                    if ((unsigned)(x0 >> 32) == want) need &= ~1;
                }
                if (need & 2) {
                    x1 = __hip_atomic_load(hsrc + tid + 256, __ATOMIC_RELAXED,
                                           __HIP_MEMORY_SCOPE_AGENT);
                    if ((unsigned)(x1 >> 32) == want) need &= ~2;
                }
                if (need & 4) {
                    x2 = __hip_atomic_load(hsrc + tid + 512, __ATOMIC_RELAXED,
                                           __HIP_MEMORY_SCOPE_AGENT);
                    if ((unsigned)(x2 >> 32) == want) need &= ~4;
                }
                if (need & 8) {
                    x3 = __hip_atomic_load(hsrc + tid + 768, __ATOMIC_RELAXED,
                                           __HIP_MEMORY_SCOPE_AGENT);
                    if ((unsigned)(x3 >> 32) == want) need &= ~8;
                }
                if (need) __builtin_amdgcn_s_sleep(1);
            } while (need);
            dst[tid]       = __uint_as_float((unsigned)x0);
            dst[tid + 256] = __uint_as_float((unsigned)x1);
            dst[tid + 512] = __uint_as_float((unsigned)x2);
            dst[tid + 768] = __uint_as_float((unsigned)x3);
        }
        __syncthreads();

        // every 8 steps: logits for the 8 rows just completed (hist[0..7])
        if ((t & 7) == 0 && t > 0 && b < 250) do_group(t - 8);

        float4 a = {0.f, 0.f, 0.f, 0.f};
#pragma unroll
        for (int k = 0; k < 16; ++k) {
            float4 w = wreg[k];
            const float* hv = &dst[(c16 + 16 * k) * 4];
            a.x += w.x * hv[0];
            a.y += w.y * hv[1];
            a.z += w.z * hv[2];
            a.w += w.w * hv[3];
        }
        float sum = (a.x + a.y) + (a.z + a.w);
        sum += __shfl_xor(sum, 1);
        sum += __shfl_xor(sum, 2);
        sum += __shfl_xor(sum, 4);
        sum += __shfl_xor(sum, 8);
        float s0 = __shfl(sum, 0);
        float s1 = __shfl(sum, 16);
        float s2 = __shfl(sum, 32);
        float s3 = __shfl(sum, 48);

        if (lane == 0) {
            float gi = s0 + xg_s[t][wv];
            float gf = s1 + xg_s[t][4 + wv];
            float gg = s2 + xg_s[t][8 + wv];
            float go = s3 + xg_s[t][12 + wv];
            float i_ = 1.f / (1.f + expf(-gi));
            float f_ = 1.f / (1.f + expf(-gf));
            float g_ = tanhf(gg);
            float o_ = 1.f / (1.f + expf(-go));
            cstate = f_ * cstate + i_ * g_;
            float hv = o_ * tanhf(cstate);
            unsigned long long pk =
                ((unsigned long long)(unsigned)(t + 1) << 32) |
                (unsigned long long)__float_as_uint(hv);
            __hip_atomic_store(hs_pk + (size_t)t * HIDDEN + hj, pk,
                               __ATOMIC_RELAXED, __HIP_MEMORY_SCOPE_AGENT);
        }
        // no trailing barrier: hist row (t)&7 written next iter after sync
    }

    // ---- tail: stage h[63] into hist[7], then final logits group (56..63)
    {
        const unsigned long long* hsrc = hs_pk + (size_t)63 * HIDDEN;
        float* dst = hist[7];
        unsigned long long x0 = 0, x1 = 0, x2 = 0, x3 = 0;
        int need = 0xF;
        do {
            if (need & 1) {
                x0 = __hip_atomic_load(hsrc + tid, __ATOMIC_RELAXED,
                                       __HIP_MEMORY_SCOPE_AGENT);
                if ((unsigned)(x0 >> 32) == 64u) need &= ~1;
            }
            if (need & 2) {
                x1 = __hip_atomic_load(hsrc + tid + 256, __ATOMIC_RELAXED,
                                       __HIP_MEMORY_SCOPE_AGENT);
                if ((unsigned)(x1 >> 32) == 64u) need &= ~2;
            }
            if (need & 4) {
                x2 = __hip_atomic_load(hsrc + tid + 512, __ATOMIC_RELAXED,
                                       __HIP_MEMORY_SCOPE_AGENT);
                if ((unsigned)(x2 >> 32) == 64u) need &= ~4;
            }
            if (need & 8) {
                x3 = __hip_atomic_load(hsrc + tid + 768, __ATOMIC_RELAXED,
                                       __HIP_MEMORY_SCOPE_AGENT);
                if ((unsigned)(x3 >> 32) == 64u) need &= ~8;
            }
            if (need) __builtin_amdgcn_s_sleep(1);
        } while (need);
        dst[tid]       = __uint_as_float((unsigned)x0);
        dst[tid + 256] = __uint_as_float((unsigned)x1);
        dst[tid + 512] = __uint_as_float((unsigned)x2);
        dst[tid + 768] = __uint_as_float((unsigned)x3);
        __syncthreads();
    }
    if (b < 250) do_group(56);
}

// ---------------------------------------------------------------------------
extern "C" void kernel_launch(void* const* d_in, const int* in_sizes, int n_in,
                              void* d_out, int out_size, void* d_ws, size_t ws_size,
                              hipStream_t stream) {
    const int*   caps  = (const int*)  d_in[0];
    const float* feat  = (const float*)d_in[1];
    const float* table = (const float*)d_in[2];
    const float* Wih   = (const float*)d_in[3];
    const float* Whh   = (const float*)d_in[4];
    const float* bih   = (const float*)d_in[5];
    const float* bhh   = (const float*)d_in[6];
    const float* fcW   = (const float*)d_in[7];
    const float* fcb   = (const float*)d_in[8];
    float* out = (float*)d_out;

    // Workspace: only hs_pk [64][1024] u64 (512 KB). No memset needed:
    // 0xAA poison never matches a valid tag (1..64).
    unsigned long long* hs_pk = (unsigned long long*)d_ws;

    decoder_fused<<<NBLK, 256, 0, stream>>>(caps, feat, table, Wih, Whh,
                                            bih, bhh, fcW, fcb, hs_pk, out);
}

// Round 6
// 653.553 us; speedup vs baseline: 1.5063x; 1.5063x over previous
//
#include <hip/hip_runtime.h>
#include <math.h>

#define EMBED  1024
#define HIDDEN 1024
#define VOCAB  32000
#define TSTEPS 64
#define NBLK   256   // 1 block per CU, all co-resident (persistent kernel)

// ---------------------------------------------------------------------------
// ONE fused persistent kernel — R4 structure (502us) with the two spin
// structures de-serialized (R6):
//   * phase-2 poll: all 4 tag-loads issued BEFORE any check -> 1 LLC RTT per
//     poll iteration instead of 4 dependent RTTs.
//   * phase-3 hs staging: all 16 words/thread/chunk issued into registers,
//     tags checked after -> ~1 RTT per chunk instead of 16 sequential spins.
// R5's 8-step interleave is REVERTED: each group re-streamed the full fcW
// slice (8x traffic, FETCH 534MB) and its barriers sat on the LSTM critical
// path. fcW is read exactly once here.
//
// Phase 1: block computes the 16 Xg columns {g*1024+4b+w} its own LSTM phase
//          consumes; xs gathered on the fly. Results -> LDS xg_s.
// Phase 2: sequential LSTM; h exchange via packed (tag=t+1, h) u64 agent-
//          scope atomics in hs_pk[64][1024] (tag+value in ONE word -> no
//          ordering needed, 1-leg latency). 0xAA poison never matches tags
//          1..64 -> no memset.
// Phase 3: logits; blocks 0..249 own 128 vocab rows; hs chunk staged with
//          batched tag-polls; fcW streamed once, coalesced.
// ---------------------------------------------------------------------------
__global__ __launch_bounds__(256, 1) void decoder_fused(
    const int*   __restrict__ caps,
    const float* __restrict__ feat,
    const float* __restrict__ table,
    const float* __restrict__ Wih,
    const float* __restrict__ Whh,
    const float* __restrict__ bih,
    const float* __restrict__ bhh,
    const float* __restrict__ fcW,
    const float* __restrict__ fcb,
    unsigned long long* hs_pk,   // [64][1024] packed (tag,value)
    float* __restrict__ out)
{
    // arena reuse:
    //   phase 1: xs_s[64][132] (33792 B) + w16[16][132] (8448 B) = 42240 B
    //   phase 3: hs_s[64][68] (17408 B) + w3[128][68] (34816 B)  = 52224 B
    __shared__ __align__(16) char arena[52224];
    __shared__ float xg_s[TSTEPS][16];
    __shared__ float h_s[2][HIDDEN];
    __shared__ int   caps_s[TSTEPS];

    int tid = threadIdx.x;
    int b   = blockIdx.x;

    // ---- phase-2 weight prefetch issued first (hides HBM under phase 1)
    int lane = tid & 63;
    int wv   = tid >> 6;          // output sub-index 0..3 (one per wave)
    int g    = lane >> 4;         // gate index 0..3 (i,f,g,o)
    int c16  = lane & 15;
    int hj   = 4 * b + wv;
    const float4* wrow = (const float4*)(Whh + ((size_t)g * HIDDEN + hj) * HIDDEN);
    float4 wreg[16];
#pragma unroll
    for (int k = 0; k < 16; ++k) wreg[k] = wrow[c16 + 16 * k];

    if (tid < TSTEPS) caps_s[tid] = caps[tid];

    // ================= phase 1: xg_s[t][r] for this block's 16 columns ====
    {
        float (*xs_s)[132] = (float (*)[132])arena;            // 64 x 132
        float (*w16)[132]  = (float (*)[132])(arena + 33792);  // 16 x 132
        int jl = tid & 15;        // r = g*4+w
        int tg = tid >> 4;        // 16 groups x 4 timesteps
        float acc4[4] = {0.f, 0.f, 0.f, 0.f};
        __syncthreads();          // caps_s visible

        for (int c = 0; c < 8; ++c) {
            __syncthreads();
            for (int idx = tid; idx < 64 * 32; idx += 256) {
                int r = idx >> 5, f4 = idx & 31;
                const float* src = (r == 0)
                    ? (feat + c * 128)
                    : (table + (size_t)caps_s[r - 1] * EMBED + c * 128);
                *((float4*)&xs_s[r][f4 * 4]) = ((const float4*)src)[f4];
            }
            for (int idx = tid; idx < 16 * 32; idx += 256) {
                int r = idx >> 5, f4 = idx & 31;
                int jr = (r >> 2) * HIDDEN + 4 * b + (r & 3);
                *((float4*)&w16[r][f4 * 4]) =
                    ((const float4*)(Wih + (size_t)jr * EMBED + c * 128))[f4];
            }
            __syncthreads();
            for (int f4 = 0; f4 < 32; ++f4) {
                float4 w = *((const float4*)&w16[jl][f4 * 4]);
#pragma unroll
                for (int k = 0; k < 4; ++k) {
                    float4 x4 = *((const float4*)&xs_s[tg * 4 + k][f4 * 4]);
                    acc4[k] += w.x * x4.x + w.y * x4.y + w.z * x4.z + w.w * x4.w;
                }
            }
        }
        int jrow = (jl >> 2) * HIDDEN + 4 * b + (jl & 3);
        float bias = bih[jrow] + bhh[jrow];
#pragma unroll
        for (int k = 0; k < 4; ++k) xg_s[tg * 4 + k][jl] = acc4[k] + bias;
        __syncthreads();
    }

    // ================= phase 2: sequential LSTM =================
    float cstate = 0.f;           // live in lane 0 of each wave only
    for (int t = 0; t < TSTEPS; ++t) {
        float* dst = h_s[t & 1];
        if (t == 0) {
            for (int i = tid; i < HIDDEN; i += 256) dst[i] = 0.f;
        } else {
            const unsigned long long* hsrc = hs_pk + (size_t)(t - 1) * HIDDEN;
            unsigned want = (unsigned)t;   // producer stored tag (t-1)+1 = t
            unsigned long long x0, x1, x2, x3;
            // batched poll: issue ALL 4 loads, then check -> 1 RTT/iteration
            for (;;) {
                x0 = __hip_atomic_load(hsrc + tid, __ATOMIC_RELAXED,
                                       __HIP_MEMORY_SCOPE_AGENT);
                x1 = __hip_atomic_load(hsrc + tid + 256, __ATOMIC_RELAXED,
                                       __HIP_MEMORY_SCOPE_AGENT);
                x2 = __hip_atomic_load(hsrc + tid + 512, __ATOMIC_RELAXED,
                                       __HIP_MEMORY_SCOPE_AGENT);
                x3 = __hip_atomic_load(hsrc + tid + 768, __ATOMIC_RELAXED,
                                       __HIP_MEMORY_SCOPE_AGENT);
                bool ok = ((unsigned)(x0 >> 32) == want) &
                          ((unsigned)(x1 >> 32) == want) &
                          ((unsigned)(x2 >> 32) == want) &
                          ((unsigned)(x3 >> 32) == want);
                if (ok) break;
                __builtin_amdgcn_s_sleep(1);
            }
            dst[tid]       = __uint_as_float((unsigned)x0);
            dst[tid + 256] = __uint_as_float((unsigned)x1);
            dst[tid + 512] = __uint_as_float((unsigned)x2);
            dst[tid + 768] = __uint_as_float((unsigned)x3);
        }
        __syncthreads();

        float4 a = {0.f, 0.f, 0.f, 0.f};
#pragma unroll
        for (int k = 0; k < 16; ++k) {
            float4 w = wreg[k];
            const float* hv = &dst[(c16 + 16 * k) * 4];
            a.x += w.x * hv[0];
            a.y += w.y * hv[1];
            a.z += w.z * hv[2];
            a.w += w.w * hv[3];
        }
        float sum = (a.x + a.y) + (a.z + a.w);
        sum += __shfl_xor(sum, 1);
        sum += __shfl_xor(sum, 2);
        sum += __shfl_xor(sum, 4);
        sum += __shfl_xor(sum, 8);
        float s0 = __shfl(sum, 0);
        float s1 = __shfl(sum, 16);
        float s2 = __shfl(sum, 32);
        float s3 = __shfl(sum, 48);

        if (lane == 0) {
            float gi = s0 + xg_s[t][wv];
            float gf = s1 + xg_s[t][4 + wv];
            float gg = s2 + xg_s[t][8 + wv];
            float go = s3 + xg_s[t][12 + wv];
            float i_ = 1.f / (1.f + expf(-gi));
            float f_ = 1.f / (1.f + expf(-gf));
            float g_ = tanhf(gg);
            float o_ = 1.f / (1.f + expf(-go));
            cstate = f_ * cstate + i_ * g_;
            float hv = o_ * tanhf(cstate);
            unsigned long long pk =
                ((unsigned long long)(unsigned)(t + 1) << 32) |
                (unsigned long long)__float_as_uint(hv);
            __hip_atomic_store(hs_pk + (size_t)t * HIDDEN + hj, pk,
                               __ATOMIC_RELAXED, __HIP_MEMORY_SCOPE_AGENT);
        }
        // no trailing barrier: h_s double-buffered, xg_s read-only
    }
    __syncthreads();

    // ================= phase 3: logits for 128 vocab rows =================
    if (b >= 250) return;         // 250 * 128 = 32000
    float (*hs_s)[68] = (float (*)[68])arena;             // 64 x 68
    float (*w3)[68]   = (float (*)[68])(arena + 17408);   // 128 x 68
    int tv = tid & 15;            // vocab sub-tile
    int tq = tid >> 4;            // timestep sub-tile
    int j0 = tv * 4;
    int i0 = tq * 4;
    int v0 = b * 128;
    float acc[4][8];
#pragma unroll
    for (int i = 0; i < 4; ++i)
#pragma unroll
        for (int j = 0; j < 8; ++j) acc[i][j] = 0.f;
    // (acc[i][j]: rows i0..i0+3, cols j0..j0+3 and j0+64..j0+67)

    int jcol  = tid & 63;         // hs column within chunk (wave-contiguous)
    int tbase = tid >> 6;         // rows tbase + 4*i

    for (int kc = 0; kc < 16; ++kc) {   // K in chunks of 64
        __syncthreads();
        // stage hs chunk [64][64]: batched tag-poll, 16 words/thread, ~1 RTT
        {
            unsigned long long v[16];
            const unsigned long long* src = hs_pk + kc * 64 + jcol;
            for (;;) {
#pragma unroll
                for (int i = 0; i < 16; ++i)
                    v[i] = __hip_atomic_load(src + (size_t)(tbase + 4 * i) * HIDDEN,
                                             __ATOMIC_RELAXED,
                                             __HIP_MEMORY_SCOPE_AGENT);
                bool ok = true;
#pragma unroll
                for (int i = 0; i < 16; ++i)
                    ok &= ((unsigned)(v[i] >> 32) == (unsigned)(tbase + 4 * i + 1));
                if (ok) break;
                __builtin_amdgcn_s_sleep(8);
            }
#pragma unroll
            for (int i = 0; i < 16; ++i)
                hs_s[tbase + 4 * i][jcol] = __uint_as_float((unsigned)v[i]);
        }
        // stage fcW chunk [128][64] — coalesced 256B bursts per row
#pragma unroll
        for (int i = 0; i < 8; ++i) {
            int idx = tid + i * 256;
            int r = idx >> 4, f4 = idx & 15;
            *((float4*)&w3[r][f4 * 4]) =
                ((const float4*)(fcW + (size_t)(v0 + r) * HIDDEN + kc * 64))[f4];
        }
        __syncthreads();
        for (int q = 0; q < 16; ++q) {
            float4 hv4[4];
#pragma unroll
            for (int i = 0; i < 4; ++i)
                hv4[i] = *((const float4*)&hs_s[i0 + i][q * 4]);
#pragma unroll
            for (int jh = 0; jh < 2; ++jh) {
#pragma unroll
                for (int j = 0; j < 4; ++j) {
                    float4 w4 = *((const float4*)&w3[jh * 64 + j0 + j][q * 4]);
#pragma unroll
                    for (int i = 0; i < 4; ++i) {
                        acc[i][jh * 4 + j] += w4.x * hv4[i].x + w4.y * hv4[i].y +
                                              w4.z * hv4[i].z + w4.w * hv4[i].w;
                    }
                }
            }
        }
    }
#pragma unroll
    for (int jh = 0; jh < 2; ++jh) {
        float b0 = fcb[v0 + jh * 64 + j0 + 0];
        float b1 = fcb[v0 + jh * 64 + j0 + 1];
        float b2 = fcb[v0 + jh * 64 + j0 + 2];
        float b3 = fcb[v0 + jh * 64 + j0 + 3];
#pragma unroll
        for (int i = 0; i < 4; ++i) {
            float4 o = {acc[i][jh * 4 + 0] + b0, acc[i][jh * 4 + 1] + b1,
                        acc[i][jh * 4 + 2] + b2, acc[i][jh * 4 + 3] + b3};
            *((float4*)&out[(size_t)(i0 + i) * VOCAB + v0 + jh * 64 + j0]) = o;
        }
    }
}

// ---------------------------------------------------------------------------
extern "C" void kernel_launch(void* const* d_in, const int* in_sizes, int n_in,
                              void* d_out, int out_size, void* d_ws, size_t ws_size,
                              hipStream_t stream) {
    const int*   caps  = (const int*)  d_in[0];
    const float* feat  = (const float*)d_in[1];
    const float* table = (const float*)d_in[2];
    const float* Wih   = (const float*)d_in[3];
    const float* Whh   = (const float*)d_in[4];
    const float* bih   = (const float*)d_in[5];
    const float* bhh   = (const float*)d_in[6];
    const float* fcW   = (const float*)d_in[7];
    const float* fcb   = (const float*)d_in[8];
    float* out = (float*)d_out;

    // Workspace: only hs_pk [64][1024] u64 (512 KB). No memset needed:
    // 0xAA poison never matches a valid tag (1..64).
    unsigned long long* hs_pk = (unsigned long long*)d_ws;

    decoder_fused<<<NBLK, 256, 0, stream>>>(caps, feat, table, Wih, Whh,
                                            bih, bhh, fcW, fcb, hs_pk, out);
}